// Round 1
// baseline (86.055 us; speedup 1.0000x reference)
//
#include <hip/hip_runtime.h>

// PointSample: bilinear grid sample, zero border.
// features: (8,128,128,256) f32, grid: (8,16384,2) f32, out: (8,16384,256) f32.

constexpr int B = 8, H = 128, W = 128, C = 256, P = 16384;

__global__ __launch_bounds__(256) void point_sample_kernel(
    const float* __restrict__ features,
    const float* __restrict__ grid,
    float* __restrict__ out)
{
    const int wave = threadIdx.x >> 6;        // 4 waves per block
    const int lane = threadIdx.x & 63;
    const int pt   = blockIdx.x * 4 + wave;   // global point id, 0 .. B*P-1
    const int b    = pt >> 14;                // / 16384
    const int p    = pt & (P - 1);

    // grid[b, p, 0] = x (W coord), grid[b, p, 1] = y (H coord)
    const float2 g = reinterpret_cast<const float2*>(grid)[b * P + p];
    const float x = g.x * (float)W - 0.5f;
    const float y = g.y * (float)H - 0.5f;
    const float fx = floorf(x), fy = floorf(y);
    const int ix = (int)fx, iy = (int)fy;
    const float frx = x - fx, fry = y - fy;

    const float w00 = (1.0f - fry) * (1.0f - frx);  // (iy  , ix  )
    const float w01 = (1.0f - fry) * frx;           // (iy  , ix+1)
    const float w10 = fry * (1.0f - frx);           // (iy+1, ix  )
    const float w11 = fry * frx;                    // (iy+1, ix+1)

    const float* fb = features + (size_t)b * H * W * C;
    const int c = lane * 4;                          // 4 channels per lane

    float4 acc = make_float4(0.f, 0.f, 0.f, 0.f);
    #pragma unroll
    for (int dy = 0; dy < 2; ++dy) {
        const int hy = iy + dy;
        const bool vy = (hy >= 0) && (hy < H);
        #pragma unroll
        for (int dx = 0; dx < 2; ++dx) {
            const int wx = ix + dx;
            // wave-uniform condition: whole wave shares one point
            if (vy && (wx >= 0) && (wx < W)) {
                const float wgt = dy ? (dx ? w11 : w10) : (dx ? w01 : w00);
                const float4 v = *reinterpret_cast<const float4*>(
                    fb + ((size_t)hy * W + wx) * C + c);
                acc.x += wgt * v.x;
                acc.y += wgt * v.y;
                acc.z += wgt * v.z;
                acc.w += wgt * v.w;
            }
        }
    }

    *reinterpret_cast<float4*>(out + (size_t)(b * P + p) * C + c) = acc;
}

extern "C" void kernel_launch(void* const* d_in, const int* in_sizes, int n_in,
                              void* d_out, int out_size, void* d_ws, size_t ws_size,
                              hipStream_t stream) {
    const float* features = (const float*)d_in[0];
    const float* grid     = (const float*)d_in[1];
    float* out            = (float*)d_out;

    const int n_points = B * P;              // 131072
    dim3 block(256);
    dim3 grd(n_points / 4);                  // 4 points (waves) per block
    point_sample_kernel<<<grd, block, 0, stream>>>(features, grid, out);
}

// Round 2
// 85.636 us; speedup vs baseline: 1.0049x; 1.0049x over previous
//
#include <hip/hip_runtime.h>

// PointSample: bilinear grid sample, zero border.
// features: (8,128,128,256) f32, grid: (8,16384,2) f32, out: (8,16384,256) f32.
// One 64-lane wave per point; lane owns 4 channels (float4).
// Output stores are non-temporal so the 131 MB write stream does not evict
// the 128 MiB features tensor from L2/L3 (fetch was 223 MB vs 135 MB ideal).

constexpr int B = 8, H = 128, W = 128, C = 256, P = 16384;

__global__ __launch_bounds__(256) void point_sample_kernel(
    const float* __restrict__ features,
    const float* __restrict__ grid,
    float* __restrict__ out)
{
    const int wave = threadIdx.x >> 6;        // 4 waves per block
    const int lane = threadIdx.x & 63;
    const int pt   = blockIdx.x * 4 + wave;   // global point id, 0 .. B*P-1
    const int b    = pt >> 14;                // / 16384
    const int p    = pt & (P - 1);

    // grid[b, p, 0] = x (W coord), grid[b, p, 1] = y (H coord). One-shot read.
    const float2* gptr = reinterpret_cast<const float2*>(grid) + (b * P + p);
    const float gx = __builtin_nontemporal_load(&gptr->x);
    const float gy = __builtin_nontemporal_load(&gptr->y);

    const float x = gx * (float)W - 0.5f;
    const float y = gy * (float)H - 0.5f;
    const float fx = floorf(x), fy = floorf(y);
    const int ix = (int)fx, iy = (int)fy;
    const float frx = x - fx, fry = y - fy;

    const float w00 = (1.0f - fry) * (1.0f - frx);  // (iy  , ix  )
    const float w01 = (1.0f - fry) * frx;           // (iy  , ix+1)
    const float w10 = fry * (1.0f - frx);           // (iy+1, ix  )
    const float w11 = fry * frx;                    // (iy+1, ix+1)

    const float* fb = features + (size_t)b * H * W * C;
    const int c = lane * 4;                          // 4 channels per lane

    float4 acc = make_float4(0.f, 0.f, 0.f, 0.f);
    #pragma unroll
    for (int dy = 0; dy < 2; ++dy) {
        const int hy = iy + dy;
        const bool vy = (hy >= 0) && (hy < H);
        #pragma unroll
        for (int dx = 0; dx < 2; ++dx) {
            const int wx = ix + dx;
            // wave-uniform condition: whole wave shares one point
            if (vy && (wx >= 0) && (wx < W)) {
                const float wgt = dy ? (dx ? w11 : w10) : (dx ? w01 : w00);
                const float4 v = *reinterpret_cast<const float4*>(
                    fb + ((size_t)hy * W + wx) * C + c);
                acc.x += wgt * v.x;
                acc.y += wgt * v.y;
                acc.z += wgt * v.z;
                acc.w += wgt * v.w;
            }
        }
    }

    // Non-temporal output store: written once, never read.
    float* op = out + (size_t)(b * P + p) * C + c;
    __builtin_nontemporal_store(acc.x, op + 0);
    __builtin_nontemporal_store(acc.y, op + 1);
    __builtin_nontemporal_store(acc.z, op + 2);
    __builtin_nontemporal_store(acc.w, op + 3);
}

extern "C" void kernel_launch(void* const* d_in, const int* in_sizes, int n_in,
                              void* d_out, int out_size, void* d_ws, size_t ws_size,
                              hipStream_t stream) {
    const float* features = (const float*)d_in[0];
    const float* grid     = (const float*)d_in[1];
    float* out            = (float*)d_out;

    const int n_points = B * P;              // 131072
    dim3 block(256);
    dim3 grd(n_points / 4);                  // 4 points (waves) per block
    point_sample_kernel<<<grd, block, 0, stream>>>(features, grid, out);
}